// Round 6
// baseline (1268.553 us; speedup 1.0000x reference)
//
#include <hip/hip_runtime.h>

// Output = conv1x1(x, refine_w, refine_b). Everything else in the reference is
// dead code (`_dead` unused; x_back == x: permutation then its argsort-inverse).
//
// x: (8, 64, 256, 256) fp32, refine_w: (64, 64) [o-major], refine_b: (64,)
// out[b,o,h,w] = sum_c w[o,c] * x[b,c,h,w] + b[o]
//
// v7 = v5's pipeline with HALVED register demand (don't fight the allocator;
// fit its budget). v5 (OPT=8, acc=32) overflowed the 64-VGPR budget at the
// allocator's 8-waves/SIMD target -> accvgpr churn (VALU 65us vs 27us floor)
// + 50MB scratch. v6's waves_per_eu pin made scheduling/liveness explode
// (2.4GB fetch). v7: 1024-thread blocks, 16 waves, OPT=4 per wave -> acc=16
// VGPRs, total live ~35: fits 64 with slack. Staging/compute/barrier
// structure identical to v5 (global_load_lds chunks, plain __syncthreads,
// no asm fences, no occupancy attributes).
// Accumulation order over c unchanged -> bit-identical results.

constexpr int  C      = 64;
constexpr long HW     = 65536;          // 256*256
constexpr long NPIX   = 8L * HW;        // 524288 pixels
constexpr int  WAVES  = 16;             // 1024-thread block
constexpr int  OPT    = C / WAVES;      // 4 output channels per wave
constexpr int  PIXB   = 256;            // pixels per block tile (64 quads)
constexpr int  CCHUNK = 16;             // channels staged per chunk (16 KB)
constexpr int  NCHUNK = C / CCHUNK;     // 4 chunks
constexpr int  CPW    = CCHUNK / WAVES; // 1 channel staged per wave per chunk

typedef float f4 __attribute__((ext_vector_type(4)));

__device__ __forceinline__ void gload_lds16(const float* g, float* l)
{
    // one instr: 64 lanes x 16B contiguous -> LDS at (uniform l) + lane*16
    __builtin_amdgcn_global_load_lds(
        (const __attribute__((address_space(1))) unsigned int*)g,
        (__attribute__((address_space(3))) unsigned int*)l,
        16, 0, 0);
}

__global__ __launch_bounds__(1024) void conv1x1_refine_kernel(
    const float* __restrict__ x,
    const float* __restrict__ w,     // (64,64) o-major
    const float* __restrict__ bias,  // (64,)
    float* __restrict__ out)
{
    __shared__ float lds[2][CCHUNK][PIXB];   // 2 x 16 KB

    const int t    = threadIdx.x;
    const int lane = t & 63;
    const int wv   = __builtin_amdgcn_readfirstlane(t >> 6);  // wave id 0..15

    const long pix0 = (long)blockIdx.x * PIXB;   // block's first pixel
    const long b    = pix0 >> 16;                // blocks never straddle a batch
    const long hw0  = pix0 & (HW - 1);

    const float* xb = x + b * ((long)C * HW) + hw0;
    float*       ob = out + b * ((long)C * HW) + (long)wv * OPT * HW + hw0;
    const float* wg = w + wv * OPT * C;          // this wave's 4 rows of w

    // wave wv stages chunk channel wv (1 KB row, one global_load_lds)
    auto stage = [&](int chunk, int buf) {
        const int cc = wv;                       // CPW == 1
        const int c  = chunk * CCHUNK + cc;
        gload_lds16(xb + (long)c * HW + (long)lane * 4, &lds[buf][cc][0]);
    };

    f4 acc[OPT];
#pragma unroll
    for (int o = 0; o < OPT; ++o) {
        const float bv = bias[wv * OPT + o];     // uniform -> s_load
        acc[o] = (f4){bv, bv, bv, bv};
    }

    stage(0, 0);
    __syncthreads();                 // chunk 0 landed, all waves

#pragma unroll
    for (int cb = 0; cb < NCHUNK; ++cb) {
        // Prefetch next chunk into the other buffer; loads fly during compute,
        // the barrier's vmcnt drain lands after the FMA block.
        if (cb + 1 < NCHUNK) stage(cb + 1, (cb + 1) & 1);

#pragma unroll
        for (int k = 0; k < CCHUNK; ++k) {
            const int c = cb * CCHUNK + k;
            const f4 xv = *reinterpret_cast<const f4*>(&lds[cb & 1][k][lane * 4]);
#pragma unroll
            for (int o = 0; o < OPT; ++o) {
                const float wvv = wg[o * C + c]; // uniform -> SGPR operand
                acc[o].x = fmaf(wvv, xv.x, acc[o].x);
                acc[o].y = fmaf(wvv, xv.y, acc[o].y);
                acc[o].z = fmaf(wvv, xv.z, acc[o].z);
                acc[o].w = fmaf(wvv, xv.w, acc[o].w);
            }
        }

        __syncthreads();   // next chunk landed + everyone done with this buf
    }

    // Streamed output, never re-read: nontemporal keeps x resident in LLC.
#pragma unroll
    for (int o = 0; o < OPT; ++o)
        __builtin_nontemporal_store(acc[o],
            reinterpret_cast<f4*>(ob + (long)o * HW + (long)lane * 4));
}

extern "C" void kernel_launch(void* const* d_in, const int* in_sizes, int n_in,
                              void* d_out, int out_size, void* d_ws, size_t ws_size,
                              hipStream_t stream)
{
    const float* x  = (const float*)d_in[0];   // x
    const float* rw = (const float*)d_in[11];  // refine_w
    const float* rb = (const float*)d_in[12];  // refine_b
    float* out = (float*)d_out;

    const int threads = 1024;
    const int blocks  = (int)(NPIX / PIXB);    // 2048
    hipLaunchKernelGGL(conv1x1_refine_kernel, dim3(blocks), dim3(threads), 0, stream,
                       x, rw, rb, out);
}

// Round 7
// 1105.220 us; speedup vs baseline: 1.1478x; 1.1478x over previous
//
#include <hip/hip_runtime.h>

// Output = conv1x1(x, refine_w, refine_b). Everything else in the reference is
// dead code (`_dead` unused; x_back == x: permutation then its argsort-inverse).
//
// x: (8, 64, 256, 256) fp32, refine_w: (64, 64) [o-major], refine_b: (64,)
// out[b,o,h,w] = sum_c w[o,c] * x[b,c,h,w] + b[o]
//
// v8 = v5 + a 128-VGPR allocator budget obtained the NON-fighting way.
// History: the consume phase's 16x ds_read_b128 gets batch-hoisted (64 VGPRs
// of xv) on top of acc(32) ~= 108 live. The allocator's budget comes from its
// LDS-derived occupancy target: at 32 KB/block it targets 8 waves/SIMD ->
// 64-reg budget -> spill (v5 mild: +49MB WRITE; v7 at 1024thr catastrophic:
// 16x traffic, ~1KB scratch/thread). Fix: 64 KB LDS (4 rotating buffers) ->
// target becomes 2 blocks x 8 waves = 4 waves/SIMD -> budget 128 >= 108.
// __launch_bounds__(512,4) states the same 4 waves/EU minimum via the
// standard path. Structure/schedule otherwise byte-identical to v5: stage
// next chunk via global_load_lds, consume current from LDS, __syncthreads.
// Accumulation order over c unchanged -> bit-identical results.

constexpr int  C      = 64;
constexpr long HW     = 65536;          // 256*256
constexpr long NPIX   = 8L * HW;        // 524288 pixels
constexpr int  WAVES  = 8;              // 512-thread block
constexpr int  OPT    = C / WAVES;      // 8 output channels per wave
constexpr int  PIXB   = 256;            // pixels per block tile (64 quads)
constexpr int  CCHUNK = 16;             // channels staged per chunk (16 KB)
constexpr int  NCHUNK = C / CCHUNK;     // 4 chunks
constexpr int  NBUF   = 4;              // 4 x 16 KB = 64 KB (sets reg budget)
constexpr int  CPW    = CCHUNK / WAVES; // 2 channels staged per wave per chunk

typedef float f4 __attribute__((ext_vector_type(4)));

__device__ __forceinline__ void gload_lds16(const float* g, float* l)
{
    // one instr: 64 lanes x 16B contiguous -> LDS at (uniform l) + lane*16
    __builtin_amdgcn_global_load_lds(
        (const __attribute__((address_space(1))) unsigned int*)g,
        (__attribute__((address_space(3))) unsigned int*)l,
        16, 0, 0);
}

__global__ __launch_bounds__(512, 4) void conv1x1_refine_kernel(
    const float* __restrict__ x,
    const float* __restrict__ w,     // (64,64) o-major
    const float* __restrict__ bias,  // (64,)
    float* __restrict__ out)
{
    __shared__ float lds[NBUF][CCHUNK][PIXB];   // 64 KB

    const int t    = threadIdx.x;
    const int lane = t & 63;
    const int wv   = __builtin_amdgcn_readfirstlane(t >> 6);  // wave id -> SGPR

    const long pix0 = (long)blockIdx.x * PIXB;   // block's first pixel
    const long b    = pix0 >> 16;                // blocks never straddle a batch
    const long hw0  = pix0 & (HW - 1);

    const float* xb = x + b * ((long)C * HW) + hw0;
    float*       ob = out + b * ((long)C * HW) + (long)wv * OPT * HW + hw0;
    const float* wg = w + wv * OPT * C;          // this wave's 8 rows of w

    // wave wv stages chunk channels [wv*2, wv*2+1] (1 KB row each)
    auto stage = [&](int chunk, int buf) {
#pragma unroll
        for (int k = 0; k < CPW; ++k) {
            const int cc = wv * CPW + k;
            const int c  = chunk * CCHUNK + cc;
            gload_lds16(xb + (long)c * HW + (long)lane * 4, &lds[buf][cc][0]);
        }
    };

    f4 acc[OPT];
#pragma unroll
    for (int o = 0; o < OPT; ++o) {
        const float bv = bias[wv * OPT + o];     // uniform -> s_load
        acc[o] = (f4){bv, bv, bv, bv};
    }

    stage(0, 0);
    __syncthreads();                 // chunk 0 landed, all waves

#pragma unroll
    for (int cb = 0; cb < NCHUNK; ++cb) {
        // Prefetch next chunk into the next rotating buffer; loads fly during
        // this chunk's FMAs, land at the barrier's vmcnt drain.
        if (cb + 1 < NCHUNK) stage(cb + 1, (cb + 1) & (NBUF - 1));

#pragma unroll
        for (int k = 0; k < CCHUNK; ++k) {
            const int c = cb * CCHUNK + k;
            const f4 xv = *reinterpret_cast<const f4*>(
                &lds[cb & (NBUF - 1)][k][lane * 4]);
#pragma unroll
            for (int o = 0; o < OPT; ++o) {
                const float wvv = wg[o * C + c]; // uniform -> SGPR operand
                acc[o].x = fmaf(wvv, xv.x, acc[o].x);
                acc[o].y = fmaf(wvv, xv.y, acc[o].y);
                acc[o].z = fmaf(wvv, xv.z, acc[o].z);
                acc[o].w = fmaf(wvv, xv.w, acc[o].w);
            }
        }

        __syncthreads();   // next chunk landed + everyone done with this buf
    }

    // Streamed output, never re-read: nontemporal keeps x resident in LLC.
#pragma unroll
    for (int o = 0; o < OPT; ++o)
        __builtin_nontemporal_store(acc[o],
            reinterpret_cast<f4*>(ob + (long)o * HW + (long)lane * 4));
}

extern "C" void kernel_launch(void* const* d_in, const int* in_sizes, int n_in,
                              void* d_out, int out_size, void* d_ws, size_t ws_size,
                              hipStream_t stream)
{
    const float* x  = (const float*)d_in[0];   // x
    const float* rw = (const float*)d_in[11];  // refine_w
    const float* rb = (const float*)d_in[12];  // refine_b
    float* out = (float*)d_out;

    const int threads = 512;
    const int blocks  = (int)(NPIX / PIXB);    // 2048
    hipLaunchKernelGGL(conv1x1_refine_kernel, dim3(blocks), dim3(threads), 0, stream,
                       x, rw, rb, out);
}

// Round 8
// 560.454 us; speedup vs baseline: 2.2634x; 1.9720x over previous
//
#include <hip/hip_runtime.h>

// Output = conv1x1(x, refine_w, refine_b). Everything else in the reference is
// dead code (`_dead` unused; x_back == x: permutation then its argsort-inverse).
//
// x: (8, 64, 256, 256) fp32, refine_w: (64, 64) [o-major], refine_b: (64,)
// out[b,o,h,w] = sum_c w[o,c] * x[b,c,h,w] + b[o]
//
// v9 = v5's geometry + hoist fences. Eight rounds of evidence: every spill
// (v2, v5 mild, v6/v7/v8 catastrophic) traces to the pre-RA scheduler
// batch-hoisting the consume phase's 16 ds_read_b128 (64 VGPRs of xv) on top
// of acc; granting MORE budget (min_waves=4 -> 128) made it hoist more and
// spill harder (v6==v8: 2.4GB fetch). Fix at the source: sched_barrier(0)
// every 4 consume iterations caps the hoist window at 16 VGPRs of xv ->
// peak pressure ~60 regs, fits the default 64-reg budget with nothing to
// spill. The k=0 fence also keeps the two stage global_load_lds pinned above
// the consume phase so HBM prefetch spans the whole FMA block.
// Accumulation order over c unchanged -> bit-identical results.

constexpr int  C      = 64;
constexpr long HW     = 65536;          // 256*256
constexpr long NPIX   = 8L * HW;        // 524288 pixels
constexpr int  WAVES  = 8;              // 512-thread block
constexpr int  OPT    = C / WAVES;      // 8 output channels per wave
constexpr int  PIXB   = 256;            // pixels per block tile (64 quads)
constexpr int  CCHUNK = 16;             // channels staged per chunk (16 KB)
constexpr int  NCHUNK = C / CCHUNK;     // 4 chunks
constexpr int  CPW    = CCHUNK / WAVES; // 2 channels staged per wave per chunk

typedef float f4 __attribute__((ext_vector_type(4)));

__device__ __forceinline__ void gload_lds16(const float* g, float* l)
{
    // one instr: 64 lanes x 16B contiguous -> LDS at (uniform l) + lane*16
    __builtin_amdgcn_global_load_lds(
        (const __attribute__((address_space(1))) unsigned int*)g,
        (__attribute__((address_space(3))) unsigned int*)l,
        16, 0, 0);
}

__global__ __launch_bounds__(512) void conv1x1_refine_kernel(
    const float* __restrict__ x,
    const float* __restrict__ w,     // (64,64) o-major
    const float* __restrict__ bias,  // (64,)
    float* __restrict__ out)
{
    __shared__ float lds[2][CCHUNK][PIXB];   // 2 x 16 KB

    const int t    = threadIdx.x;
    const int lane = t & 63;
    const int wv   = __builtin_amdgcn_readfirstlane(t >> 6);  // wave id -> SGPR

    const long pix0 = (long)blockIdx.x * PIXB;   // block's first pixel
    const long b    = pix0 >> 16;                // blocks never straddle a batch
    const long hw0  = pix0 & (HW - 1);

    const float* xb = x + b * ((long)C * HW) + hw0;
    float*       ob = out + b * ((long)C * HW) + (long)wv * OPT * HW + hw0;
    const float* wg = w + wv * OPT * C;          // this wave's 8 rows of w

    // wave wv stages chunk channels [wv*2, wv*2+1] (1 KB row each)
    auto stage = [&](int chunk, int buf) {
#pragma unroll
        for (int k = 0; k < CPW; ++k) {
            const int cc = wv * CPW + k;
            const int c  = chunk * CCHUNK + cc;
            gload_lds16(xb + (long)c * HW + (long)lane * 4, &lds[buf][cc][0]);
        }
    };

    f4 acc[OPT];
#pragma unroll
    for (int o = 0; o < OPT; ++o) {
        const float bv = bias[wv * OPT + o];     // uniform -> s_load
        acc[o] = (f4){bv, bv, bv, bv};
    }

    stage(0, 0);
    __syncthreads();                 // chunk 0 landed, all waves

#pragma unroll
    for (int cb = 0; cb < NCHUNK; ++cb) {
        // Prefetch next chunk into the other buffer; the k=0 fence below pins
        // these loads above the consume phase, so they fly during the FMAs.
        if (cb + 1 < NCHUNK) stage(cb + 1, (cb + 1) & 1);

#pragma unroll
        for (int k = 0; k < CCHUNK; ++k) {
            // Bound the scheduler's ds_read hoist window to 4 reads (16 VGPRs):
            // without this, all 16 reads get batch-hoisted (64 VGPRs) on top
            // of acc and the allocator spills (v5-v8 post-mortems).
            if ((k & 3) == 0) __builtin_amdgcn_sched_barrier(0);

            const int c = cb * CCHUNK + k;
            const f4 xv = *reinterpret_cast<const f4*>(&lds[cb & 1][k][lane * 4]);
#pragma unroll
            for (int o = 0; o < OPT; ++o) {
                const float wvv = wg[o * C + c]; // uniform -> SGPR operand
                acc[o].x = fmaf(wvv, xv.x, acc[o].x);
                acc[o].y = fmaf(wvv, xv.y, acc[o].y);
                acc[o].z = fmaf(wvv, xv.z, acc[o].z);
                acc[o].w = fmaf(wvv, xv.w, acc[o].w);
            }
        }

        __syncthreads();   // next chunk landed + everyone done with this buf
    }

    // Streamed output, never re-read: nontemporal keeps x resident in LLC.
#pragma unroll
    for (int o = 0; o < OPT; ++o)
        __builtin_nontemporal_store(acc[o],
            reinterpret_cast<f4*>(ob + (long)o * HW + (long)lane * 4));
}

extern "C" void kernel_launch(void* const* d_in, const int* in_sizes, int n_in,
                              void* d_out, int out_size, void* d_ws, size_t ws_size,
                              hipStream_t stream)
{
    const float* x  = (const float*)d_in[0];   // x
    const float* rw = (const float*)d_in[11];  // refine_w
    const float* rb = (const float*)d_in[12];  // refine_b
    float* out = (float*)d_out;

    const int threads = 512;
    const int blocks  = (int)(NPIX / PIXB);    // 2048
    hipLaunchKernelGGL(conv1x1_refine_kernel, dim3(blocks), dim3(threads), 0, stream,
                       x, rw, rb, out);
}